// Round 8
// baseline (2012.917 us; speedup 1.0000x reference)
//
#include <hip/hip_runtime.h>
#include <math.h>

// Problem constants (fixed by setup_inputs)
#define NB 64
#define NC 256
#define NHW 16
#define NE 8192
#define NUMEL 4194304          // 64*256*16*16
#define LOSS_OFF 4194304
#define CNT_OFF  4194305

typedef __bf16 bf16x8 __attribute__((ext_vector_type(8)));
typedef float  f32x4  __attribute__((ext_vector_type(4)));

#define GLOAD_LDS(gptr, lptr) \
  __builtin_amdgcn_global_load_lds( \
      (const __attribute__((address_space(1))) unsigned int*)(gptr), \
      (__attribute__((address_space(3))) unsigned int*)(lptr), 16, 0, 0)

// ---------------- helpers ----------------
__device__ __forceinline__ float cubicw(float t) {
  // torch bicubic, a = -0.75
  t = fabsf(t);
  if (t <= 1.0f) return (1.25f * t - 2.25f) * t * t + 1.0f;
  if (t < 2.0f)  return ((-0.75f * t + 3.75f) * t - 6.0f) * t + 3.0f;
  return 0.0f;
}

__device__ __forceinline__ short f2bf(float x) {
  union { float f; unsigned int u; } v; v.f = x;
  unsigned int r = v.u + 0x7fffu + ((v.u >> 16) & 1u);  // RNE
  return (short)(r >> 16);
}
__device__ __forceinline__ float bf2f(short h) {
  union { float f; unsigned int u; } v;
  v.u = ((unsigned int)(unsigned short)h) << 16;
  return v.f;
}

// ---------------- prep kernels ----------------
// zero loss + counts region of d_out
__global__ void k_zero(float* a, int na) {
  int i = blockIdx.x * 256 + threadIdx.x;
  if (i < na) a[i] = 0.0f;
}

// z (NCHW) -> z_rest NHWC [16384][256]
__global__ void k_tr_in(const float* __restrict__ z, float* __restrict__ zrest) {
  int n = blockIdx.x, c = threadIdx.x;
  int b = n >> 8, hw = n & 255;
  zrest[(size_t)n * 256 + c] = z[((size_t)(b * 256 + c)) * 256 + hw];
}

// embedding [8192][256] -> B2 [8192][768] bf16 rows = [hi, hi, lo]; esq[8192] fp32
__global__ void k_prep_emb2(const float* __restrict__ emb, short* __restrict__ B2,
                            float* __restrict__ esq) {
  int j = blockIdx.x, t = threadIdx.x;
  float v = emb[(size_t)j * 256 + t];
  short hi = f2bf(v);
  short lo = f2bf(v - bf2f(hi));
  B2[(size_t)j * 768 + t]       = hi;
  B2[(size_t)j * 768 + 256 + t] = hi;
  B2[(size_t)j * 768 + 512 + t] = lo;
  __shared__ float red[256];
  red[t] = v * v;
  __syncthreads();
  for (int s = 128; s > 0; s >>= 1) { if (t < s) red[t] += red[t + s]; __syncthreads(); }
  if (t == 0) esq[j] = red[0];
}

// conv_w [si][o][i][kh][kw] -> wB2 [si][tap][o][512] bf16 rows = [hi(256), lo(256)]
__global__ void k_prep_wb(const float* __restrict__ w, short* __restrict__ wB2) {
  int m = blockIdx.x * 256 + threadIdx.x;
  if (m >= 8 * 9 * 65536) return;
  int i = m & 255, o = (m >> 8) & 255;
  int r = m >> 16;            // si*9 + tap
  int si = r / 9, tap = r % 9;
  float v = w[(((size_t)si * 256 + o) * 256 + i) * 9 + tap];
  short hi = f2bf(v);
  short lo = f2bf(v - bf2f(hi));
  size_t dst = ((size_t)r * 256 + o) * 512;
  wB2[dst + i]       = hi;
  wB2[dst + 256 + i] = lo;
}

// ---------------- per-scale kernels ----------------
// area downsample: z_rest NHWC -> A2 rows [hi, lo, hi]
__global__ void k_down_a2(const float* __restrict__ zrest, short* __restrict__ A2, int pn) {
  int pq = blockIdx.x, b = blockIdx.y, c = threadIdx.x;
  int p = pq / pn, q = pq % pn;
  int sp = (p * 16) / pn, ep = ((p + 1) * 16 + pn - 1) / pn;
  int sq = (q * 16) / pn, eq = ((q + 1) * 16 + pn - 1) / pn;
  float s = 0.0f;
  for (int h = sp; h < ep; h++)
    for (int w = sq; w < eq; w++)
      s += zrest[((size_t)((b * 16 + h) * 16 + w)) * 256 + c];
  float x = s / (float)((ep - sp) * (eq - sq));
  int n = (b * pn + p) * pn + q;
  short hi = f2bf(x);
  short lo = f2bf(x - bf2f(hi));
  A2[(size_t)n * 768 + c]       = hi;
  A2[(size_t)n * 768 + 256 + c] = lo;
  A2[(size_t)n * 768 + 512 + c] = hi;
}

// identity (last scale): z_rest NHWC -> A2
__global__ void k_split_a2(const float* __restrict__ zrest, short* __restrict__ A2) {
  int n = blockIdx.x, c = threadIdx.x;
  float x = zrest[(size_t)n * 256 + c];
  short hi = f2bf(x);
  short lo = f2bf(x - bf2f(hi));
  A2[(size_t)n * 768 + c]       = hi;
  A2[(size_t)n * 768 + 256 + c] = lo;
  A2[(size_t)n * 768 + 512 + c] = hi;
}

// MFMA distance GEMM + fused argmin — UNCHANGED from R7 (frozen at ~303us;
// five sync variants all land 300-330 -> local plateau; this round targets
// conv). Ring-4 BK=32 depth-3 counted vmcnt(8), pair-row swizzled LDS,
// hoisted addressing, lgkmcnt(0) discipline.
__global__ __launch_bounds__(512, 2) void k_dist_mfma(
    const short* __restrict__ A2, const short* __restrict__ B2,
    const float* __restrict__ esq, float* __restrict__ pd, int* __restrict__ pi,
    int N) {
  __shared__ short As[4][8192];   // 4 x 16KB ring, pair-row layout [128][64]
  __shared__ short Bs[4][8192];   // 4 x 16KB
  int t = threadIdx.x, ln = t & 63, wv = t >> 6;
  int wr = wv >> 2, wc = wv & 3;      // row-half, code-quarter
  int n0 = blockIdx.x * 256;
  int jb0 = blockIdx.y * 256;
  int lc = ln & 15, lq = ln >> 4;

  // --- staging descriptors (per-lane global src, wave-uniform LDS dst) ---
  const short* gA[2]; const short* gB[2]; int ldst[2];
#pragma unroll
  for (int i = 0; i < 2; i++) {
    int C = i * 512 + wv * 64 + ln;      // linear 16B chunk 0..1023
    int L = C >> 3, c5s = C & 7;
    int c5g = c5s ^ (L & 7);             // inverse swizzle on the source
    int rowg = (L << 1) | (c5g >> 2), ccg = c5g & 3;
    gA[i] = A2 + (size_t)(n0 + rowg) * 768 + ccg * 8;
    gB[i] = B2 + (size_t)(jb0 + rowg) * 768 + ccg * 8;
    ldst[i] = (i * 512 + wv * 64) * 8;   // shorts, wave-uniform
  }
  // --- LDS read offsets (shorts; constant per thread) ---
  int offA[2][4], offB[4];
#pragma unroll
  for (int rt = 0; rt < 4; rt++) {
#pragma unroll
    for (int h = 0; h < 2; h++) {
      int row = wr * 128 + h * 64 + rt * 16 + lc;
      int L = row >> 1;
      int swc = (((row & 1) << 2) + lq) ^ (L & 7);
      offA[h][rt] = L * 64 + swc * 8;
    }
    int rowb = wc * 64 + rt * 16 + lc;
    int Lb = rowb >> 1;
    int swb = (((rowb & 1) << 2) + lq) ^ (Lb & 7);
    offB[rt] = Lb * 64 + swb * 8;
  }

  f32x4 acc[8][4];
#pragma unroll
  for (int at = 0; at < 8; at++)
#pragma unroll
    for (int ac = 0; ac < 4; ac++) acc[at][ac] = (f32x4)(0.0f);

#define DSTAGE_A(tile_, bsel_)                                        \
  {                                                                   \
    _Pragma("unroll")                                                 \
    for (int i = 0; i < 2; i++)                                       \
      GLOAD_LDS(gA[i] + (tile_) * 32, &As[(bsel_)][ldst[i]]);         \
  }
#define DSTAGE_B(tile_, bsel_)                                        \
  {                                                                   \
    _Pragma("unroll")                                                 \
    for (int i = 0; i < 2; i++)                                       \
      GLOAD_LDS(gB[i] + (tile_) * 32, &Bs[(bsel_)][ldst[i]]);         \
  }

  // prologue: stage tiles 0,1,2 (12 loads/wave); vmcnt(8) -> tile0 landed
  DSTAGE_A(0, 0); DSTAGE_B(0, 0);
  DSTAGE_A(1, 1); DSTAGE_B(1, 1);
  DSTAGE_A(2, 2); DSTAGE_B(2, 2);
  asm volatile("s_waitcnt vmcnt(8)" ::: "memory");
  __builtin_amdgcn_s_barrier();

#pragma unroll
  for (int kt = 0; kt < 24; kt++) {
    const int bsel = kt & 3;
    const short* aBase = &As[bsel][0];
    const short* bBase = &Bs[bsel][0];
    // ---- P0: stage A(kt+3); read fa-half0 + all fb ----
    if (kt < 21) DSTAGE_A(kt + 3, (kt + 3) & 3);
    bf16x8 fa0[4], fb[4];
#pragma unroll
    for (int rt = 0; rt < 4; rt++)
      fa0[rt] = *(const bf16x8*)(aBase + offA[0][rt]);
#pragma unroll
    for (int ct = 0; ct < 4; ct++)
      fb[ct] = *(const bf16x8*)(bBase + offB[ct]);
    __builtin_amdgcn_s_barrier();
    asm volatile("s_waitcnt lgkmcnt(0)" ::: "memory");  // all frags resident
    __builtin_amdgcn_s_setprio(1);
#pragma unroll
    for (int rt = 0; rt < 4; rt++)
#pragma unroll
      for (int ct = 0; ct < 4; ct++)
        acc[rt][ct] = __builtin_amdgcn_mfma_f32_16x16x32_bf16(
            fa0[rt], fb[ct], acc[rt][ct], 0, 0, 0);
    __builtin_amdgcn_s_setprio(0);
    __builtin_amdgcn_s_barrier();
    // ---- P1: stage B(kt+3); read fa-half1; fb reused ----
    if (kt < 21) DSTAGE_B(kt + 3, (kt + 3) & 3);
    bf16x8 fa1[4];
#pragma unroll
    for (int rt = 0; rt < 4; rt++)
      fa1[rt] = *(const bf16x8*)(aBase + offA[1][rt]);
    __builtin_amdgcn_s_barrier();
    asm volatile("s_waitcnt lgkmcnt(0)" ::: "memory");
    __builtin_amdgcn_s_setprio(1);
#pragma unroll
    for (int rt = 0; rt < 4; rt++)
#pragma unroll
      for (int ct = 0; ct < 4; ct++)
        acc[4 + rt][ct] = __builtin_amdgcn_mfma_f32_16x16x32_bf16(
            fa1[rt], fb[ct], acc[4 + rt][ct], 0, 0, 0);
    __builtin_amdgcn_s_setprio(0);
    // ---- end of K-tile: counted wait (never 0 until the tail) ----
    if (kt < 23) {
      if (kt < 21)       { asm volatile("s_waitcnt vmcnt(8)" ::: "memory"); }
      else if (kt == 21) { asm volatile("s_waitcnt vmcnt(4)" ::: "memory"); }
      else               { asm volatile("s_waitcnt vmcnt(0)" ::: "memory"); }
      __builtin_amdgcn_s_barrier();
    }
  }
#undef DSTAGE_A
#undef DSTAGE_B

  // epilogue: dist = esq[j] - 2*dot; per-row argmin. Reuse As[0] as the
  // cross-wave reduce scratch (sbd: 4KB floats, sbi: 4KB ints) — disjoint
  // from As[3]/Bs[3] still being read by trailing waves in kt=23.
  float* sbd = (float*)(&As[0][0]);
  int*   sbi = (int*)((char*)(&As[0][0]) + 4096);

#pragma unroll
  for (int at = 0; at < 8; at++) {
    float bst[4]; int bix[4];
#pragma unroll
    for (int r = 0; r < 4; r++) { bst[r] = 3.4e38f; bix[r] = 0; }
#pragma unroll
    for (int ac = 0; ac < 4; ac++) {
      int j = jb0 + wc * 64 + ac * 16 + lc;
      float es = esq[j];
#pragma unroll
      for (int r = 0; r < 4; r++) {
        float d = es - 2.0f * acc[at][ac][r];
        if (d < bst[r]) { bst[r] = d; bix[r] = j; }  // ac asc => j asc, '<' keeps low j
      }
    }
#pragma unroll
    for (int r = 0; r < 4; r++) {
      float bd = bst[r]; int bi = bix[r];
#pragma unroll
      for (int off = 1; off < 16; off <<= 1) {
        float od = __shfl_xor(bd, off, 64);
        int   oi = __shfl_xor(bi, off, 64);
        if (od < bd || (od == bd && oi < bi)) { bd = od; bi = oi; }
      }
      if (lc == 0) {
        int rl = wr * 128 + at * 16 + lq * 4 + r;
        sbd[wc * 256 + rl] = bd;
        sbi[wc * 256 + rl] = bi;
      }
    }
  }
  __syncthreads();
  // combine the 4 code-quarters (wc ascending = ascending j; explicit tiebreak)
  if (t < 256) {
    float b0 = sbd[t]; int i0 = sbi[t];
#pragma unroll
    for (int w = 1; w < 4; w++) {
      float b1 = sbd[w * 256 + t]; int i1 = sbi[w * 256 + t];
      if (b1 < b0 || (b1 == b0 && i1 < i0)) { b0 = b1; i0 = i1; }
    }
    int n = n0 + t;
    if (n < N) {
      pd[(size_t)n * 32 + blockIdx.y] = b0;
      pi[(size_t)n * 32 + blockIdx.y] = i0;
    }
  }
}

// reduce per-row partials over 32 code tiles -> idx, counts
__global__ void k_red(const float* __restrict__ pd, const int* __restrict__ pi,
                      int* __restrict__ idxb, float* __restrict__ counts, int N, int nct) {
  int n = blockIdx.x * 256 + threadIdx.x;
  if (n >= N) return;
  float bd = pd[(size_t)n * nct]; int bi = pi[(size_t)n * nct];
  for (int jt = 1; jt < nct; jt++) {
    float d = pd[(size_t)n * nct + jt]; int ii = pi[(size_t)n * nct + jt];
    if (d < bd || (d == bd && ii < bi)) { bd = d; bi = ii; }
  }
  idxb[n] = bi;
  atomicAdd(counts + bi, 1.0f);
}

// gather + bicubic upsample -> zu fp32 NHWC and zu2 [hi(256), lo(256)]
__global__ void k_up(const float* __restrict__ emb, const int* __restrict__ idxb,
                     float* __restrict__ zu, short* __restrict__ zu2, int pn, int last) {
  int n = blockIdx.x, c = threadIdx.x;
  float acc;
  if (last) {
    acc = emb[(size_t)idxb[n] * 256 + c];
  } else {
    int b = n >> 8, hw = n & 255, h = hw >> 4, w = hw & 15;
    float scale = pn / 16.0f;
    float xh = (h + 0.5f) * scale - 0.5f; int fh = (int)floorf(xh);
    float xw = (w + 0.5f) * scale - 0.5f; int fw = (int)floorf(xw);
    int ph[4], pw[4]; float wh[4], wwt[4];
#pragma unroll
    for (int k = 0; k < 4; k++) {
      wh[k] = cubicw(xh - (float)(fh + k - 1));
      int pp = fh + k - 1; ph[k] = min(max(pp, 0), pn - 1);
      wwt[k] = cubicw(xw - (float)(fw + k - 1));
      pp = fw + k - 1; pw[k] = min(max(pp, 0), pn - 1);
    }
    acc = 0.0f;
#pragma unroll
    for (int kh = 0; kh < 4; kh++)
#pragma unroll
      for (int kw = 0; kw < 4; kw++) {
        int row = idxb[(n >> 8) * pn * pn + ph[kh] * pn + pw[kw]];
        acc += wh[kh] * wwt[kw] * emb[(size_t)row * 256 + c];
      }
  }
  zu[(size_t)n * 256 + c] = acc;
  short hi = f2bf(acc);
  short lo = f2bf(acc - bf2f(hi));
  zu2[(size_t)n * 512 + c]       = hi;
  zu2[(size_t)n * 512 + 256 + c] = lo;
}

// 3x3 SAME conv — R17: term-fused compensated MFMA GEMM.
// Same three products as the old 768-K scheme (hi·hi + lo·hi + hi·lo; only
// summation order changes), but layouts are [hi,lo] (512): staging bytes
// -33%, reads/MFMA 0.75 -> 0.5, steps 108 -> 72, 24 MFMA per barrier-pair.
// Block = 256 thr / 4 waves, tile 32px (2 image rows) x 256o; grid 512
// (64 img x 8 row-pairs) -> TRUE 2 blocks/CU (LDS 74KB, acc only 32 AGPR):
// co-resident unsynced blocks overlap each other's drains.
// Step (kc 8 x tap 9): read 12 b128 (fa_hi/lo x2pf, fb_hi/lo x4ct from
// pair-row-swizzled LDS) + stage next step's B (dbuf) -> barrier ->
// lgkmcnt(0) -> 24 MFMA (3 terms x 8 frags) -> [tap8: halo rewrite] ->
// vmcnt(0)+lgkm+barrier (drain issued ~600cyc earlier; L2-resident weights).
// Halo [72 pos][hi32|lo32] single-buffered, restaged per kc via regs
// (issue at tap0, write after tap8's post-MFMA barrier).
__global__ __launch_bounds__(256, 2) void k_conv_mfma(
    const short* __restrict__ zu2, const short* __restrict__ wB2,
    const float* __restrict__ cb, const float* __restrict__ zu,
    float* __restrict__ zrest, float* __restrict__ out_loss, int si) {
  __shared__ short Ah[72 * 64];      // 9 KB: halo, 128B rows, chunk^(row&7)
  __shared__ short Bs[2][2][8192];   // 64 KB: [buf][part][128 pair-rows][64sh]
  __shared__ float red[256];         // 1 KB
  int t = threadIdx.x, ln = t & 63, wv = t >> 6;   // 4 waves, o-quarter wv
  int lc = ln & 15, lq = ln >> 4;
  int b = blockIdx.x >> 3, r0 = (blockIdx.x & 7) * 2;

  // --- halo staging descriptors: 576 chunks of 16B over <=3 slots/thread ---
  bool hen[3], hval[3]; const short* hsrc[3]; int hdst[3];
#pragma unroll
  for (int i = 0; i < 3; i++) {
    int l = i * 256 + t;               // 0..767; halo has 576 chunks
    hen[i] = (l < 576);
    int hrow = l >> 3, c3 = l & 7;     // hrow<72 when hen
    int part = c3 >> 2, cc = c3 & 3;
    int hh = hrow / 18, wx = hrow - hh * 18;
    int h = r0 + hh - 1, w = wx - 1;
    hval[i] = hen[i] && h >= 0 && h < 16 && w >= 0 && w < 16;
    int n = hval[i] ? (b * 256 + h * 16 + w) : 0;
    hsrc[i] = zu2 + (size_t)n * 512 + part * 256 + cc * 8;
    hdst[i] = (hrow * 8 + (c3 ^ (hrow & 7))) * 8;
  }
  // --- B staging descriptors (pair-row swizzle; per part 1024 chunks) ---
  const short* gB[4]; int bdst[4];
#pragma unroll
  for (int i = 0; i < 4; i++) {
    int C = i * 256 + t;
    int L = C >> 3, c5s = C & 7;
    int c5g = c5s ^ (L & 7);
    int row = (L << 1) | (c5g >> 2), cc = c5g & 3;
    gB[i] = wB2 + ((size_t)si * 9 * 256 + row) * 512 + cc * 8;
    bdst[i] = C * 8;
  }
  // --- fb read offsets ---
  int offB[4];
#pragma unroll
  for (int ct = 0; ct < 4; ct++) {
    int row = wv * 64 + ct * 16 + lc;
    int L = row >> 1;
    int swc = (((row & 1) << 2) | lq) ^ (L & 7);
    offB[ct] = L * 64 + swc * 8;
  }

// stage B panel (tap_, kc_, both parts) into dbuf slot buf_ (8 calls/wave)
#define CSTAGE(tap_, kc_, buf_)                                             \
  {                                                                         \
    _Pragma("unroll")                                                       \
    for (int p = 0; p < 2; p++)                                             \
      _Pragma("unroll")                                                     \
      for (int i = 0; i < 4; i++)                                           \
        GLOAD_LDS(gB[i] + (size_t)(tap_) * 131072 + p * 256 + (kc_) * 32,   \
                  &Bs[(buf_)][p][bdst[i]]);                                 \
  }

  f32x4 acc[2][4];
#pragma unroll
  for (int pf = 0; pf < 2; pf++)
#pragma unroll
    for (int ct = 0; ct < 4; ct++) acc[pf][ct] = (f32x4)(0.0f);

  // ---- prologue: halo(kc0) via regs + B(step 0) ----
  {
    uint4 hv[3];
#pragma unroll
    for (int i = 0; i < 3; i++) {
      hv[i] = make_uint4(0u, 0u, 0u, 0u);
      if (hval[i]) hv[i] = *(const uint4*)(hsrc[i]);
    }
    CSTAGE(0, 0, 0);
    asm volatile("s_waitcnt vmcnt(8)" ::: "memory");  // forces the 3 reg loads
#pragma unroll
    for (int i = 0; i < 3; i++)
      if (hen[i]) *(uint4*)(&Ah[hdst[i]]) = hv[i];
    asm volatile("s_waitcnt vmcnt(0) lgkmcnt(0)" ::: "memory");
  }
  __builtin_amdgcn_s_barrier();

  for (int kc = 0; kc < 8; kc++) {
    uint4 nh[3];
#pragma unroll
    for (int i = 0; i < 3; i++) nh[i] = make_uint4(0u, 0u, 0u, 0u);
#pragma unroll
    for (int tap = 0; tap < 9; tap++) {
      const int s = kc * 9 + tap;
      const int buf = s & 1;
      const int dh = tap / 3 - 1, dw = tap % 3 - 1;
      // --- fragment reads (12 b128) ---
      bf16x8 fahi[2], falo[2], fbhi[4], fblo[4];
#pragma unroll
      for (int pf = 0; pf < 2; pf++) {
        int hrow = (pf + dh + 1) * 18 + lc + dw + 1;
        int base = hrow * 64, sw = hrow & 7;
        fahi[pf] = *(const bf16x8*)(Ah + base + (lq ^ sw) * 8);
        falo[pf] = *(const bf16x8*)(Ah + base + ((4 + lq) ^ sw) * 8);
      }
#pragma unroll
      for (int ct = 0; ct < 4; ct++) {
        fbhi[ct] = *(const bf16x8*)(&Bs[buf][0][offB[ct]]);
        fblo[ct] = *(const bf16x8*)(&Bs[buf][1][offB[ct]]);
      }
      // --- stage next step's B into the other dbuf half ---
      if (s < 71) {
        int nt = (tap < 8) ? tap + 1 : 0;
        int nk = (tap < 8) ? kc : kc + 1;
        CSTAGE(nt, nk, buf ^ 1);
      }
      // --- halo pipeline: issue next-kc loads at tap 0 ---
      if (tap == 0 && kc < 7) {
#pragma unroll
        for (int i = 0; i < 3; i++)
          if (hval[i]) nh[i] = *(const uint4*)(hsrc[i] + (kc + 1) * 32);
      }
      __builtin_amdgcn_s_barrier();
      asm volatile("s_waitcnt lgkmcnt(0)" ::: "memory");  // frags resident
      __builtin_amdgcn_s_setprio(1);
#pragma unroll
      for (int pf = 0; pf < 2; pf++)
#pragma unroll
        for (int ct = 0; ct < 4; ct++)
          acc[pf][ct] = __builtin_amdgcn_mfma_f32_16x16x32_bf16(
              fahi[pf], fbhi[ct], acc[pf][ct], 0, 0, 0);
#pragma unroll
      for (int pf = 0; pf < 2; pf++)
#pragma unroll
        for (int ct = 0; ct < 4; ct++)
          acc[pf][ct] = __builtin_amdgcn_mfma_f32_16x16x32_bf16(
              falo[pf], fbhi[ct], acc[pf][ct], 0, 0, 0);
#pragma unroll
      for (int pf = 0; pf < 2; pf++)
#pragma unroll
        for (int ct = 0; ct < 4; ct++)
          acc[pf][ct] = __builtin_amdgcn_mfma_f32_16x16x32_bf16(
              fahi[pf], fblo[ct], acc[pf][ct], 0, 0, 0);
      __builtin_amdgcn_s_setprio(0);
      // --- halo rewrite at tap 8 (single buffer; all reads done) ---
      if (tap == 8 && kc < 7) {
        __builtin_amdgcn_s_barrier();   // every wave past its fa reads
#pragma unroll
        for (int i = 0; i < 3; i++)
          if (hen[i]) *(uint4*)(&Ah[hdst[i]]) = nh[i];
      }
      // --- end of step: drain staging + (tap8) halo writes; sync ---
      if (s < 71) {
        asm volatile("s_waitcnt vmcnt(0) lgkmcnt(0)" ::: "memory");
        __builtin_amdgcn_s_barrier();
      }
    }
  }
#undef CSTAGE
  __syncthreads();

  // --- epilogue: bias + residual update + loss ---
  float lsum = 0.0f;
#pragma unroll
  for (int ct = 0; ct < 4; ct++) {
    int o = wv * 64 + ct * 16 + lc;
    float bias = cb[si * 256 + o];
#pragma unroll
    for (int pf = 0; pf < 2; pf++) {
#pragma unroll
      for (int r = 0; r < 4; r++) {
        int px = pf * 16 + lq * 4 + r;
        int n = b * 256 + (r0 + (px >> 4)) * 16 + (px & 15);
        size_t m = (size_t)n * 256 + o;
        float y = acc[pf][ct][r] + bias;
        float res = 0.5f * (zu[m] + y);
        float nv = zrest[m] - res;
        zrest[m] = nv;
        lsum += nv * nv;
      }
    }
  }
  red[t] = lsum;
  __syncthreads();
  for (int s = 128; s > 0; s >>= 1) { if (t < s) red[t] += red[t + s]; __syncthreads(); }
  if (t == 0) atomicAdd(out_loss, red[0] * (0.25f / (8.0f * 4194304.0f)));
}

// out NCHW = z - z_rest (z_hat_cum)
__global__ void k_out(const float* __restrict__ z, const float* __restrict__ zrest,
                      float* __restrict__ out) {
  int n = blockIdx.x, c = threadIdx.x;
  int b = n >> 8, hw = n & 255;
  size_t m = ((size_t)(b * 256 + c)) * 256 + hw;
  out[m] = z[m] - zrest[(size_t)n * 256 + c];
}

// ---------------- launch ----------------
extern "C" void kernel_launch(void* const* d_in, const int* in_sizes, int n_in,
                              void* d_out, int out_size, void* d_ws, size_t ws_size,
                              hipStream_t stream) {
  const float* z   = (const float*)d_in[0];
  const float* emb = (const float*)d_in[1];
  const float* cw  = (const float*)d_in[2];
  const float* cb  = (const float*)d_in[3];
  float* out = (float*)d_out;
  float* ws  = (float*)d_ws;

  // layout (floats): proven-safe envelope ~104 MB
  float* z_rest = ws;                        // 4,194,304
  float* zu     = ws + 4194304;              // 4,194,304
  float* esq    = ws + 8388608;              // 8,192
  short* A2     = (short*)(ws + 8396800);    // 16384*768 shorts (dist A)
  short* zu2    = A2;                        // reuse: 16384*512 shorts (conv A)
  short* B2     = (short*)(ws + 14688256);   // 8192*768 shorts
  short* wB2    = (short*)(ws + 17833984);   // 8*9*256*512 shorts (fits old region)
  float* pd     = ws + 24911872;             // 16384*32 = 524,288
  int*   pi     = (int*)(ws + 25436160);     // 524,288
  int*   idxb   = (int*)(ws + 25960448);     // 16,384

  const int pns[8] = {1, 2, 3, 4, 6, 8, 12, 16};

  k_zero<<<33, 256, 0, stream>>>(out + LOSS_OFF, 1 + NE);
  k_tr_in<<<16384, 256, 0, stream>>>(z, z_rest);
  k_prep_emb2<<<8192, 256, 0, stream>>>(emb, B2, esq);
  k_prep_wb<<<18432, 256, 0, stream>>>(cw, wB2);

  for (int si = 0; si < 8; si++) {
    int pn = pns[si];
    int N = 64 * pn * pn;
    if (si < 7)
      k_down_a2<<<dim3(pn * pn, 64), 256, 0, stream>>>(z_rest, A2, pn);
    else
      k_split_a2<<<16384, 256, 0, stream>>>(z_rest, A2);
    int rb = (N + 255) / 256;
    k_dist_mfma<<<dim3(rb, 32), 512, 0, stream>>>(A2, B2, esq, pd, pi, N);
    k_red<<<(N + 255) / 256, 256, 0, stream>>>(pd, pi, idxb, out + CNT_OFF, N, 32);
    k_up<<<16384, 256, 0, stream>>>(emb, idxb, zu, zu2, pn, si == 7 ? 1 : 0);
    k_conv_mfma<<<dim3(512), 256, 0, stream>>>(zu2, wB2, cb, zu, z_rest,
                                               out + LOSS_OFF, si);
  }
  k_out<<<16384, 256, 0, stream>>>(z, z_rest, out);
}

// Round 9
// 1907.062 us; speedup vs baseline: 1.0555x; 1.0555x over previous
//
#include <hip/hip_runtime.h>
#include <math.h>

// Problem constants (fixed by setup_inputs)
#define NB 64
#define NC 256
#define NHW 16
#define NE 8192
#define NUMEL 4194304          // 64*256*16*16
#define LOSS_OFF 4194304
#define CNT_OFF  4194305

typedef __bf16 bf16x8 __attribute__((ext_vector_type(8)));
typedef float  f32x4  __attribute__((ext_vector_type(4)));

#define GLOAD_LDS(gptr, lptr) \
  __builtin_amdgcn_global_load_lds( \
      (const __attribute__((address_space(1))) unsigned int*)(gptr), \
      (__attribute__((address_space(3))) unsigned int*)(lptr), 16, 0, 0)

// ---------------- helpers ----------------
__device__ __forceinline__ float cubicw(float t) {
  // torch bicubic, a = -0.75
  t = fabsf(t);
  if (t <= 1.0f) return (1.25f * t - 2.25f) * t * t + 1.0f;
  if (t < 2.0f)  return ((-0.75f * t + 3.75f) * t - 6.0f) * t + 3.0f;
  return 0.0f;
}

__device__ __forceinline__ short f2bf(float x) {
  union { float f; unsigned int u; } v; v.f = x;
  unsigned int r = v.u + 0x7fffu + ((v.u >> 16) & 1u);  // RNE
  return (short)(r >> 16);
}
__device__ __forceinline__ float bf2f(short h) {
  union { float f; unsigned int u; } v;
  v.u = ((unsigned int)(unsigned short)h) << 16;
  return v.f;
}

// ---------------- prep kernels ----------------
// zero loss + counts region of d_out
__global__ void k_zero(float* a, int na) {
  int i = blockIdx.x * 256 + threadIdx.x;
  if (i < na) a[i] = 0.0f;
}

// z (NCHW) -> z_rest NHWC [16384][256]
__global__ void k_tr_in(const float* __restrict__ z, float* __restrict__ zrest) {
  int n = blockIdx.x, c = threadIdx.x;
  int b = n >> 8, hw = n & 255;
  zrest[(size_t)n * 256 + c] = z[((size_t)(b * 256 + c)) * 256 + hw];
}

// embedding [8192][256] -> B2 [8192][768] bf16 rows = [hi, hi, lo]; esq[8192] fp32
__global__ void k_prep_emb2(const float* __restrict__ emb, short* __restrict__ B2,
                            float* __restrict__ esq) {
  int j = blockIdx.x, t = threadIdx.x;
  float v = emb[(size_t)j * 256 + t];
  short hi = f2bf(v);
  short lo = f2bf(v - bf2f(hi));
  B2[(size_t)j * 768 + t]       = hi;
  B2[(size_t)j * 768 + 256 + t] = hi;
  B2[(size_t)j * 768 + 512 + t] = lo;
  __shared__ float red[256];
  red[t] = v * v;
  __syncthreads();
  for (int s = 128; s > 0; s >>= 1) { if (t < s) red[t] += red[t + s]; __syncthreads(); }
  if (t == 0) esq[j] = red[0];
}

// conv_w [si][o][i][kh][kw] -> wB2 [si][tap][o][768] bf16 rows = [hi, hi, lo]
__global__ void k_prep_wb(const float* __restrict__ w, short* __restrict__ wB2) {
  int m = blockIdx.x * 256 + threadIdx.x;
  if (m >= 8 * 9 * 65536) return;
  int i = m & 255, o = (m >> 8) & 255;
  int r = m >> 16;            // si*9 + tap
  int si = r / 9, tap = r % 9;
  float v = w[(((size_t)si * 256 + o) * 256 + i) * 9 + tap];
  short hi = f2bf(v);
  short lo = f2bf(v - bf2f(hi));
  size_t dst = ((size_t)r * 256 + o) * 768;
  wB2[dst + i]       = hi;
  wB2[dst + 256 + i] = hi;
  wB2[dst + 512 + i] = lo;
}

// ---------------- per-scale kernels ----------------
// area downsample: z_rest NHWC -> A2 rows [hi, lo, hi]
__global__ void k_down_a2(const float* __restrict__ zrest, short* __restrict__ A2, int pn) {
  int pq = blockIdx.x, b = blockIdx.y, c = threadIdx.x;
  int p = pq / pn, q = pq % pn;
  int sp = (p * 16) / pn, ep = ((p + 1) * 16 + pn - 1) / pn;
  int sq = (q * 16) / pn, eq = ((q + 1) * 16 + pn - 1) / pn;
  float s = 0.0f;
  for (int h = sp; h < ep; h++)
    for (int w = sq; w < eq; w++)
      s += zrest[((size_t)((b * 16 + h) * 16 + w)) * 256 + c];
  float x = s / (float)((ep - sp) * (eq - sq));
  int n = (b * pn + p) * pn + q;
  short hi = f2bf(x);
  short lo = f2bf(x - bf2f(hi));
  A2[(size_t)n * 768 + c]       = hi;
  A2[(size_t)n * 768 + 256 + c] = lo;
  A2[(size_t)n * 768 + 512 + c] = hi;
}

// identity (last scale): z_rest NHWC -> A2
__global__ void k_split_a2(const float* __restrict__ zrest, short* __restrict__ A2) {
  int n = blockIdx.x, c = threadIdx.x;
  float x = zrest[(size_t)n * 256 + c];
  short hi = f2bf(x);
  short lo = f2bf(x - bf2f(hi));
  A2[(size_t)n * 768 + c]       = hi;
  A2[(size_t)n * 768 + 256 + c] = lo;
  A2[(size_t)n * 768 + 512 + c] = hi;
}

// MFMA distance GEMM + fused argmin — frozen R7 structure (~300us, best of
// five sync variants). Ring-4 BK=32 depth-3 counted vmcnt(8), pair-row
// swizzled LDS, hoisted addressing, lgkmcnt(0) discipline.
__global__ __launch_bounds__(512, 2) void k_dist_mfma(
    const short* __restrict__ A2, const short* __restrict__ B2,
    const float* __restrict__ esq, float* __restrict__ pd, int* __restrict__ pi,
    int N) {
  __shared__ short As[4][8192];   // 4 x 16KB ring, pair-row layout [128][64]
  __shared__ short Bs[4][8192];   // 4 x 16KB
  int t = threadIdx.x, ln = t & 63, wv = t >> 6;
  int wr = wv >> 2, wc = wv & 3;      // row-half, code-quarter
  int n0 = blockIdx.x * 256;
  int jb0 = blockIdx.y * 256;
  int lc = ln & 15, lq = ln >> 4;

  // --- staging descriptors (per-lane global src, wave-uniform LDS dst) ---
  const short* gA[2]; const short* gB[2]; int ldst[2];
#pragma unroll
  for (int i = 0; i < 2; i++) {
    int C = i * 512 + wv * 64 + ln;      // linear 16B chunk 0..1023
    int L = C >> 3, c5s = C & 7;
    int c5g = c5s ^ (L & 7);             // inverse swizzle on the source
    int rowg = (L << 1) | (c5g >> 2), ccg = c5g & 3;
    gA[i] = A2 + (size_t)(n0 + rowg) * 768 + ccg * 8;
    gB[i] = B2 + (size_t)(jb0 + rowg) * 768 + ccg * 8;
    ldst[i] = (i * 512 + wv * 64) * 8;   // shorts, wave-uniform
  }
  // --- LDS read offsets (shorts; constant per thread) ---
  int offA[2][4], offB[4];
#pragma unroll
  for (int rt = 0; rt < 4; rt++) {
#pragma unroll
    for (int h = 0; h < 2; h++) {
      int row = wr * 128 + h * 64 + rt * 16 + lc;
      int L = row >> 1;
      int swc = (((row & 1) << 2) + lq) ^ (L & 7);
      offA[h][rt] = L * 64 + swc * 8;
    }
    int rowb = wc * 64 + rt * 16 + lc;
    int Lb = rowb >> 1;
    int swb = (((rowb & 1) << 2) + lq) ^ (Lb & 7);
    offB[rt] = Lb * 64 + swb * 8;
  }

  f32x4 acc[8][4];
#pragma unroll
  for (int at = 0; at < 8; at++)
#pragma unroll
    for (int ac = 0; ac < 4; ac++) acc[at][ac] = (f32x4)(0.0f);

#define DSTAGE_A(tile_, bsel_)                                        \
  {                                                                   \
    _Pragma("unroll")                                                 \
    for (int i = 0; i < 2; i++)                                       \
      GLOAD_LDS(gA[i] + (tile_) * 32, &As[(bsel_)][ldst[i]]);         \
  }
#define DSTAGE_B(tile_, bsel_)                                        \
  {                                                                   \
    _Pragma("unroll")                                                 \
    for (int i = 0; i < 2; i++)                                       \
      GLOAD_LDS(gB[i] + (tile_) * 32, &Bs[(bsel_)][ldst[i]]);         \
  }

  // prologue: stage tiles 0,1,2 (12 loads/wave); vmcnt(8) -> tile0 landed
  DSTAGE_A(0, 0); DSTAGE_B(0, 0);
  DSTAGE_A(1, 1); DSTAGE_B(1, 1);
  DSTAGE_A(2, 2); DSTAGE_B(2, 2);
  asm volatile("s_waitcnt vmcnt(8)" ::: "memory");
  __builtin_amdgcn_s_barrier();

#pragma unroll
  for (int kt = 0; kt < 24; kt++) {
    const int bsel = kt & 3;
    const short* aBase = &As[bsel][0];
    const short* bBase = &Bs[bsel][0];
    // ---- P0: stage A(kt+3); read fa-half0 + all fb ----
    if (kt < 21) DSTAGE_A(kt + 3, (kt + 3) & 3);
    bf16x8 fa0[4], fb[4];
#pragma unroll
    for (int rt = 0; rt < 4; rt++)
      fa0[rt] = *(const bf16x8*)(aBase + offA[0][rt]);
#pragma unroll
    for (int ct = 0; ct < 4; ct++)
      fb[ct] = *(const bf16x8*)(bBase + offB[ct]);
    __builtin_amdgcn_s_barrier();
    asm volatile("s_waitcnt lgkmcnt(0)" ::: "memory");  // all frags resident
    __builtin_amdgcn_s_setprio(1);
#pragma unroll
    for (int rt = 0; rt < 4; rt++)
#pragma unroll
      for (int ct = 0; ct < 4; ct++)
        acc[rt][ct] = __builtin_amdgcn_mfma_f32_16x16x32_bf16(
            fa0[rt], fb[ct], acc[rt][ct], 0, 0, 0);
    __builtin_amdgcn_s_setprio(0);
    __builtin_amdgcn_s_barrier();
    // ---- P1: stage B(kt+3); read fa-half1; fb reused ----
    if (kt < 21) DSTAGE_B(kt + 3, (kt + 3) & 3);
    bf16x8 fa1[4];
#pragma unroll
    for (int rt = 0; rt < 4; rt++)
      fa1[rt] = *(const bf16x8*)(aBase + offA[1][rt]);
    __builtin_amdgcn_s_barrier();
    asm volatile("s_waitcnt lgkmcnt(0)" ::: "memory");
    __builtin_amdgcn_s_setprio(1);
#pragma unroll
    for (int rt = 0; rt < 4; rt++)
#pragma unroll
      for (int ct = 0; ct < 4; ct++)
        acc[4 + rt][ct] = __builtin_amdgcn_mfma_f32_16x16x32_bf16(
            fa1[rt], fb[ct], acc[4 + rt][ct], 0, 0, 0);
    __builtin_amdgcn_s_setprio(0);
    // ---- end of K-tile: counted wait (never 0 until the tail) ----
    if (kt < 23) {
      if (kt < 21)       { asm volatile("s_waitcnt vmcnt(8)" ::: "memory"); }
      else if (kt == 21) { asm volatile("s_waitcnt vmcnt(4)" ::: "memory"); }
      else               { asm volatile("s_waitcnt vmcnt(0)" ::: "memory"); }
      __builtin_amdgcn_s_barrier();
    }
  }
#undef DSTAGE_A
#undef DSTAGE_B

  // epilogue: dist = esq[j] - 2*dot; per-row argmin. Reuse As[0] as the
  // cross-wave reduce scratch (sbd: 4KB floats, sbi: 4KB ints) — disjoint
  // from As[3]/Bs[3] still being read by trailing waves in kt=23.
  float* sbd = (float*)(&As[0][0]);
  int*   sbi = (int*)((char*)(&As[0][0]) + 4096);

#pragma unroll
  for (int at = 0; at < 8; at++) {
    float bst[4]; int bix[4];
#pragma unroll
    for (int r = 0; r < 4; r++) { bst[r] = 3.4e38f; bix[r] = 0; }
#pragma unroll
    for (int ac = 0; ac < 4; ac++) {
      int j = jb0 + wc * 64 + ac * 16 + lc;
      float es = esq[j];
#pragma unroll
      for (int r = 0; r < 4; r++) {
        float d = es - 2.0f * acc[at][ac][r];
        if (d < bst[r]) { bst[r] = d; bix[r] = j; }  // ac asc => j asc, '<' keeps low j
      }
    }
#pragma unroll
    for (int r = 0; r < 4; r++) {
      float bd = bst[r]; int bi = bix[r];
#pragma unroll
      for (int off = 1; off < 16; off <<= 1) {
        float od = __shfl_xor(bd, off, 64);
        int   oi = __shfl_xor(bi, off, 64);
        if (od < bd || (od == bd && oi < bi)) { bd = od; bi = oi; }
      }
      if (lc == 0) {
        int rl = wr * 128 + at * 16 + lq * 4 + r;
        sbd[wc * 256 + rl] = bd;
        sbi[wc * 256 + rl] = bi;
      }
    }
  }
  __syncthreads();
  // combine the 4 code-quarters (wc ascending = ascending j; explicit tiebreak)
  if (t < 256) {
    float b0 = sbd[t]; int i0 = sbi[t];
#pragma unroll
    for (int w = 1; w < 4; w++) {
      float b1 = sbd[w * 256 + t]; int i1 = sbi[w * 256 + t];
      if (b1 < b0 || (b1 == b0 && i1 < i0)) { b0 = b1; i0 = i1; }
    }
    int n = n0 + t;
    if (n < N) {
      pd[(size_t)n * 32 + blockIdx.y] = b0;
      pi[(size_t)n * 32 + blockIdx.y] = i0;
    }
  }
}

// reduce per-row partials over 32 code tiles -> idx, counts
__global__ void k_red(const float* __restrict__ pd, const int* __restrict__ pi,
                      int* __restrict__ idxb, float* __restrict__ counts, int N, int nct) {
  int n = blockIdx.x * 256 + threadIdx.x;
  if (n >= N) return;
  float bd = pd[(size_t)n * nct]; int bi = pi[(size_t)n * nct];
  for (int jt = 1; jt < nct; jt++) {
    float d = pd[(size_t)n * nct + jt]; int ii = pi[(size_t)n * nct + jt];
    if (d < bd || (d == bd && ii < bi)) { bd = d; bi = ii; }
  }
  idxb[n] = bi;
  atomicAdd(counts + bi, 1.0f);
}

// gather + bicubic upsample -> zu fp32 NHWC and zu2 compensated [hi,lo,hi]
__global__ void k_up(const float* __restrict__ emb, const int* __restrict__ idxb,
                     float* __restrict__ zu, short* __restrict__ zu2, int pn, int last) {
  int n = blockIdx.x, c = threadIdx.x;
  float acc;
  if (last) {
    acc = emb[(size_t)idxb[n] * 256 + c];
  } else {
    int b = n >> 8, hw = n & 255, h = hw >> 4, w = hw & 15;
    float scale = pn / 16.0f;
    float xh = (h + 0.5f) * scale - 0.5f; int fh = (int)floorf(xh);
    float xw = (w + 0.5f) * scale - 0.5f; int fw = (int)floorf(xw);
    int ph[4], pw[4]; float wh[4], wwt[4];
#pragma unroll
    for (int k = 0; k < 4; k++) {
      wh[k] = cubicw(xh - (float)(fh + k - 1));
      int pp = fh + k - 1; ph[k] = min(max(pp, 0), pn - 1);
      wwt[k] = cubicw(xw - (float)(fw + k - 1));
      pp = fw + k - 1; pw[k] = min(max(pp, 0), pn - 1);
    }
    acc = 0.0f;
#pragma unroll
    for (int kh = 0; kh < 4; kh++)
#pragma unroll
      for (int kw = 0; kw < 4; kw++) {
        int row = idxb[(n >> 8) * pn * pn + ph[kh] * pn + pw[kw]];
        acc += wh[kh] * wwt[kw] * emb[(size_t)row * 256 + c];
      }
  }
  zu[(size_t)n * 256 + c] = acc;
  short hi = f2bf(acc);
  short lo = f2bf(acc - bf2f(hi));
  zu2[(size_t)n * 768 + c]       = hi;
  zu2[(size_t)n * 768 + 256 + c] = lo;
  zu2[(size_t)n * 768 + 512 + c] = hi;
}

// 3x3 SAME conv as compensated-bf16 MFMA GEMM — R16 (best measured):
// o-split grid dim3(256,2), 256 thr / 4 waves, B panel 128o x 64, ring-3
// counted vmcnt, LDS 76KB -> 2 blocks/CU, lgkmcnt(0) before MFMA cluster.
__global__ __launch_bounds__(256, 2) void k_conv_mfma(
    const short* __restrict__ zu2, const short* __restrict__ wB2,
    const float* __restrict__ cb, const float* __restrict__ zu,
    float* __restrict__ zrest, float* __restrict__ out_loss, int si) {
  __shared__ short Ah[2][108 * 64];   // 27 KB  (6*18 halo rows x 64 sh)
  __shared__ short Bs[3][128 * 64];   // 48 KB
  __shared__ float red[256];          // 1 KB
  int t = threadIdx.x, ln = t & 63, wv = t >> 6;
  int pxh = wv >> 1, oq = wv & 1;
  int lc = ln & 15, lq = ln >> 4;
  int b = blockIdx.x >> 2, h0 = (blockIdx.x & 3) * 4;
  int o0 = blockIdx.y * 128;

  // per-thread A-halo staging descriptors (4 chunks of 16B; kc-invariant)
  bool awr[4], aval[4]; const short* asrc[4]; int adst[4];
#pragma unroll
  for (int i = 0; i < 4; i++) {
    int c = i * 256 + t;               // 0..1023; halo has 864 chunks
    int rh = c >> 3, cc = c & 7;
    int hh = rh / 18, wx = rh - hh * 18;
    int h = h0 + hh - 1, w = wx - 1;
    awr[i]  = (c < 864);
    aval[i] = awr[i] && (h >= 0) && (h < 16) && (w >= 0) && (w < 16);
    int n = aval[i] ? (b * 256 + h * 16 + w) : 0;
    asrc[i] = zu2 + (size_t)n * 768 + cc * 8;
    adst[i] = rh * 64 + (cc ^ (rh & 7)) * 8;
  }

// stage B panel (tap nt_, k-chunk nk_) into ring slot bsel_ (4 calls/wave)
#define CSTAGE(nt_, nk_, bsel_)                                             \
  {                                                                         \
    const short* bbase =                                                    \
        wB2 + (((size_t)si * 9 + (nt_)) * 256 + o0) * 768 + (nk_) * 64;     \
    _Pragma("unroll")                                                       \
    for (int i = 0; i < 4; i++) {                                           \
      int Lb = i * 256 + wv * 64;                                           \
      int L = Lb + ln;                                                      \
      int row = L >> 3, cc = L & 7;                                         \
      int gc = cc ^ (row & 7);                                              \
      GLOAD_LDS(bbase + (size_t)row * 768 + gc * 8, &Bs[(bsel_)][Lb * 8]);  \
    }                                                                       \
  }

  f32x4 acc[2][4];
#pragma unroll
  for (int pf = 0; pf < 2; pf++)
#pragma unroll
    for (int ct = 0; ct < 4; ct++) acc[pf][ct] = (f32x4)(0.0f);

  // ---- prologue: A-halo kc0 loads, B(s=0), B(s=1); vmcnt(4) forces A+B0 ----
  {
    uint4 a[4];
#pragma unroll
    for (int i = 0; i < 4; i++) {
      a[i] = make_uint4(0u, 0u, 0u, 0u);
      if (aval[i]) a[i] = *(const uint4*)(asrc[i]);
    }
    CSTAGE(0, 0, 0);
    CSTAGE(1, 0, 1);
    asm volatile("s_waitcnt vmcnt(8)" ::: "memory");  // forces the 4 A loads
#pragma unroll
    for (int i = 0; i < 4; i++)
      if (awr[i]) *(uint4*)(&Ah[0][adst[i]]) = a[i];
    asm volatile("s_waitcnt vmcnt(4) lgkmcnt(0)" ::: "memory");  // B0 + halo
  }
  __builtin_amdgcn_s_barrier();

  for (int kc = 0; kc < 12; kc++) {
    int ab = kc & 1;
    uint4 na[4];
#pragma unroll
    for (int i = 0; i < 4; i++) na[i] = make_uint4(0u, 0u, 0u, 0u);
#pragma unroll
    for (int tap = 0; tap < 9; tap++) {
      const int rb3 = tap % 3;            // read buffer (s%3)
      const int sb3 = (tap + 2) % 3;      // stage buffer ((s+2)%3)
      int dh = tap / 3 - 1, dw = tap % 3 - 1;
      // --- fragment reads for this step ---
      bf16x8 fa[2][2], fb[2][4];
#pragma unroll
      for (int ks = 0; ks < 2; ks++) {
#pragma unroll
        for (int pf = 0; pf < 2; pf++) {
          int rh = (pxh * 2 + pf + dh + 1) * 18 + lc + dw + 1;
          int cc = (ks * 4 + lq) ^ (rh & 7);
          fa[ks][pf] = *(const bf16x8*)(&Ah[ab][rh * 64 + cc * 8]);
        }
#pragma unroll
        for (int ct = 0; ct < 4; ct++) {
          int row = oq * 64 + ct * 16 + lc;
          int cc = (ks * 4 + lq) ^ (lc & 7);
          fb[ks][ct] = *(const bf16x8*)(&Bs[rb3][row * 64 + cc * 8]);
        }
      }
      // --- stage B for step s+2 (s+2 <= 107) ---
      if (kc < 11 || tap < 7) {
        int nt = (tap < 7) ? tap + 2 : tap - 7;
        int nk = (tap < 7) ? kc : kc + 1;
        CSTAGE(nt, nk, sb3);
      }
      // --- A-halo pipeline: issue loads early (tap 0), write late (tap 8) ---
      if (tap == 0 && kc < 11) {
        int koff = (kc + 1) * 64;
#pragma unroll
        for (int i = 0; i < 4; i++)
          if (aval[i]) na[i] = *(const uint4*)(asrc[i] + koff);
      }
      if (tap == 8 && kc < 11) {
#pragma unroll
        for (int i = 0; i < 4; i++)
          if (awr[i]) *(uint4*)(&Ah[ab ^ 1][adst[i]]) = na[i];
      }
      __builtin_amdgcn_s_barrier();
      asm volatile("s_waitcnt lgkmcnt(0)" ::: "memory");  // frags resident
      __builtin_amdgcn_s_setprio(1);
#pragma unroll
      for (int ks = 0; ks < 2; ks++)
#pragma unroll
        for (int pf = 0; pf < 2; pf++)
#pragma unroll
          for (int ct = 0; ct < 4; ct++)
            acc[pf][ct] = __builtin_amdgcn_mfma_f32_16x16x32_bf16(
                fa[ks][pf], fb[ks][ct], acc[pf][ct], 0, 0, 0);
      __builtin_amdgcn_s_setprio(0);
      // --- end of step: counted wait (see header); lgkm drain at tap 8 ---
      if (tap <= 1) {
        if (kc < 11) { asm volatile("s_waitcnt vmcnt(8)" ::: "memory"); }
        else         { asm volatile("s_waitcnt vmcnt(4)" ::: "memory"); }
        __builtin_amdgcn_s_barrier();
      } else if (tap <= 6) {
        asm volatile("s_waitcnt vmcnt(4)" ::: "memory");
        __builtin_amdgcn_s_barrier();
      } else if (tap == 7) {
        if (kc < 11) { asm volatile("s_waitcnt vmcnt(4)" ::: "memory"); }
        else         { asm volatile("s_waitcnt vmcnt(0)" ::: "memory"); }
        __builtin_amdgcn_s_barrier();
      } else {  // tap == 8
        if (kc < 11) {
          asm volatile("s_waitcnt vmcnt(4) lgkmcnt(0)" ::: "memory");
          __builtin_amdgcn_s_barrier();
        }
        // kc==11: last step — fall through to epilogue syncthreads
      }
    }
  }
#undef CSTAGE
  __syncthreads();

  // --- epilogue: bias + residual update + loss ---
  float lsum = 0.0f;
#pragma unroll
  for (int ct = 0; ct < 4; ct++) {
    int o = o0 + oq * 64 + ct * 16 + lc;
    float bias = cb[si * 256 + o];
#pragma unroll
    for (int pf = 0; pf < 2; pf++) {
      int n = b * 256 + (h0 + pxh * 2 + pf) * 16;
#pragma unroll
      for (int r = 0; r < 4; r++) {
        size_t m = (size_t)(n + lq * 4 + r) * 256 + o;
        float y = acc[pf][ct][r] + bias;
        float res = 0.5f * (zu[m] + y);
        float nv = zrest[m] - res;
        zrest[m] = nv;
        lsum += nv * nv;
      }
    }
  }
  red[t] = lsum;
  __syncthreads();
  for (int s = 128; s > 0; s >>= 1) { if (t < s) red[t] += red[t + s]; __syncthreads(); }
  if (t == 0) atomicAdd(out_loss, red[0] * (0.25f / (8.0f * 4194304.0f)));
}

// out NCHW = z - z_rest (z_hat_cum)
__global__ void k_out(const float* __restrict__ z, const float* __restrict__ zrest,
                      float* __restrict__ out) {
  int n = blockIdx.x, c = threadIdx.x;
  int b = n >> 8, hw = n & 255;
  size_t m = ((size_t)(b * 256 + c)) * 256 + hw;
  out[m] = z[m] - zrest[(size_t)n * 256 + c];
}

// ---------------- launch ----------------
extern "C" void kernel_launch(void* const* d_in, const int* in_sizes, int n_in,
                              void* d_out, int out_size, void* d_ws, size_t ws_size,
                              hipStream_t stream) {
  const float* z   = (const float*)d_in[0];
  const float* emb = (const float*)d_in[1];
  const float* cw  = (const float*)d_in[2];
  const float* cb  = (const float*)d_in[3];
  float* out = (float*)d_out;
  float* ws  = (float*)d_ws;

  // layout: 25,976,832 floats = 103.9 MB (proven-safe envelope: R1 used 112 MB)
  float* z_rest = ws;                        // 4,194,304
  float* zu     = ws + 4194304;              // 4,194,304
  float* esq    = ws + 8388608;              // 8,192
  short* A2     = (short*)(ws + 8396800);    // 16384*768 shorts = 6,291,456 floats
  short* zu2    = A2;                        // reuses A2 (free after dist)
  short* B2     = (short*)(ws + 14688256);   // 8192*768 shorts  = 3,145,728 floats
  short* wB2    = (short*)(ws + 17833984);   // 8*9*256*768 shorts = 7,077,888 floats
  float* pd     = ws + 24911872;             // 16384*32 = 524,288
  int*   pi     = (int*)(ws + 25436160);     // 524,288
  int*   idxb   = (int*)(ws + 25960448);     // 16,384

  const int pns[8] = {1, 2, 3, 4, 6, 8, 12, 16};

  k_zero<<<33, 256, 0, stream>>>(out + LOSS_OFF, 1 + NE);
  k_tr_in<<<16384, 256, 0, stream>>>(z, z_rest);
  k_prep_emb2<<<8192, 256, 0, stream>>>(emb, B2, esq);
  k_prep_wb<<<18432, 256, 0, stream>>>(cw, wB2);

  for (int si = 0; si < 8; si++) {
    int pn = pns[si];
    int N = 64 * pn * pn;
    if (si < 7)
      k_down_a2<<<dim3(pn * pn, 64), 256, 0, stream>>>(z_rest, A2, pn);
    else
      k_split_a2<<<16384, 256, 0, stream>>>(z_rest, A2);
    int rb = (N + 255) / 256;
    k_dist_mfma<<<dim3(rb, 32), 512, 0, stream>>>(A2, B2, esq, pd, pi, N);
    k_red<<<(N + 255) / 256, 256, 0, stream>>>(pd, pi, idxb, out + CNT_OFF, N, 32);
    k_up<<<16384, 256, 0, stream>>>(emb, idxb, zu, zu2, pn, si == 7 ? 1 : 0);
    k_conv_mfma<<<dim3(256, 2), 256, 0, stream>>>(zu2, wB2, cb, zu, z_rest,
                                                  out + LOSS_OFF, si);
  }
  k_out<<<16384, 256, 0, stream>>>(z, z_rest, out);
}

// Round 10
// 1862.252 us; speedup vs baseline: 1.0809x; 1.0241x over previous
//
#include <hip/hip_runtime.h>
#include <math.h>

// Problem constants (fixed by setup_inputs)
#define NB 64
#define NC 256
#define NHW 16
#define NE 8192
#define NUMEL 4194304          // 64*256*16*16
#define LOSS_OFF 4194304
#define CNT_OFF  4194305

typedef __bf16 bf16x8 __attribute__((ext_vector_type(8)));
typedef float  f32x4  __attribute__((ext_vector_type(4)));

#define GLOAD_LDS(gptr, lptr) \
  __builtin_amdgcn_global_load_lds( \
      (const __attribute__((address_space(1))) unsigned int*)(gptr), \
      (__attribute__((address_space(3))) unsigned int*)(lptr), 16, 0, 0)

// ---------------- helpers ----------------
__device__ __forceinline__ float cubicw(float t) {
  // torch bicubic, a = -0.75
  t = fabsf(t);
  if (t <= 1.0f) return (1.25f * t - 2.25f) * t * t + 1.0f;
  if (t < 2.0f)  return ((-0.75f * t + 3.75f) * t - 6.0f) * t + 3.0f;
  return 0.0f;
}

__device__ __forceinline__ short f2bf(float x) {
  union { float f; unsigned int u; } v; v.f = x;
  unsigned int r = v.u + 0x7fffu + ((v.u >> 16) & 1u);  // RNE
  return (short)(r >> 16);
}
__device__ __forceinline__ float bf2f(short h) {
  union { float f; unsigned int u; } v;
  v.u = ((unsigned int)(unsigned short)h) << 16;
  return v.f;
}

// ---------------- prep kernels ----------------
// zero loss + counts region of d_out
__global__ void k_zero(float* a, int na) {
  int i = blockIdx.x * 256 + threadIdx.x;
  if (i < na) a[i] = 0.0f;
}

// z (NCHW) -> z_rest NHWC [16384][256]
__global__ void k_tr_in(const float* __restrict__ z, float* __restrict__ zrest) {
  int n = blockIdx.x, c = threadIdx.x;
  int b = n >> 8, hw = n & 255;
  zrest[(size_t)n * 256 + c] = z[((size_t)(b * 256 + c)) * 256 + hw];
}

// embedding [8192][256] -> B2 [8192][768] bf16 rows = [hi, hi, lo]; esq[8192] fp32
__global__ void k_prep_emb2(const float* __restrict__ emb, short* __restrict__ B2,
                            float* __restrict__ esq) {
  int j = blockIdx.x, t = threadIdx.x;
  float v = emb[(size_t)j * 256 + t];
  short hi = f2bf(v);
  short lo = f2bf(v - bf2f(hi));
  B2[(size_t)j * 768 + t]       = hi;
  B2[(size_t)j * 768 + 256 + t] = hi;
  B2[(size_t)j * 768 + 512 + t] = lo;
  __shared__ float red[256];
  red[t] = v * v;
  __syncthreads();
  for (int s = 128; s > 0; s >>= 1) { if (t < s) red[t] += red[t + s]; __syncthreads(); }
  if (t == 0) esq[j] = red[0];
}

// conv_w [si][o][i][kh][kw] -> wB2 [si][tap][o][768] bf16 rows = [hi, hi, lo]
__global__ void k_prep_wb(const float* __restrict__ w, short* __restrict__ wB2) {
  int m = blockIdx.x * 256 + threadIdx.x;
  if (m >= 8 * 9 * 65536) return;
  int i = m & 255, o = (m >> 8) & 255;
  int r = m >> 16;            // si*9 + tap
  int si = r / 9, tap = r % 9;
  float v = w[(((size_t)si * 256 + o) * 256 + i) * 9 + tap];
  short hi = f2bf(v);
  short lo = f2bf(v - bf2f(hi));
  size_t dst = ((size_t)r * 256 + o) * 768;
  wB2[dst + i]       = hi;
  wB2[dst + 256 + i] = hi;
  wB2[dst + 512 + i] = lo;
}

// ---------------- per-scale kernels ----------------
// area downsample: z_rest NHWC -> A2 rows [hi, lo, hi]
__global__ void k_down_a2(const float* __restrict__ zrest, short* __restrict__ A2, int pn) {
  int pq = blockIdx.x, b = blockIdx.y, c = threadIdx.x;
  int p = pq / pn, q = pq % pn;
  int sp = (p * 16) / pn, ep = ((p + 1) * 16 + pn - 1) / pn;
  int sq = (q * 16) / pn, eq = ((q + 1) * 16 + pn - 1) / pn;
  float s = 0.0f;
  for (int h = sp; h < ep; h++)
    for (int w = sq; w < eq; w++)
      s += zrest[((size_t)((b * 16 + h) * 16 + w)) * 256 + c];
  float x = s / (float)((ep - sp) * (eq - sq));
  int n = (b * pn + p) * pn + q;
  short hi = f2bf(x);
  short lo = f2bf(x - bf2f(hi));
  A2[(size_t)n * 768 + c]       = hi;
  A2[(size_t)n * 768 + 256 + c] = lo;
  A2[(size_t)n * 768 + 512 + c] = hi;
}

// identity (last scale): z_rest NHWC -> A2
__global__ void k_split_a2(const float* __restrict__ zrest, short* __restrict__ A2) {
  int n = blockIdx.x, c = threadIdx.x;
  float x = zrest[(size_t)n * 256 + c];
  short hi = f2bf(x);
  short lo = f2bf(x - bf2f(hi));
  A2[(size_t)n * 768 + c]       = hi;
  A2[(size_t)n * 768 + 256 + c] = lo;
  A2[(size_t)n * 768 + 512 + c] = hi;
}

// MFMA distance GEMM + fused argmin — frozen R7 structure (~300us, best of
// five sync variants). Ring-4 BK=32 depth-3 counted vmcnt(8), pair-row
// swizzled LDS, hoisted addressing, lgkmcnt(0) discipline.
__global__ __launch_bounds__(512, 2) void k_dist_mfma(
    const short* __restrict__ A2, const short* __restrict__ B2,
    const float* __restrict__ esq, float* __restrict__ pd, int* __restrict__ pi,
    int N) {
  __shared__ short As[4][8192];   // 4 x 16KB ring, pair-row layout [128][64]
  __shared__ short Bs[4][8192];   // 4 x 16KB
  int t = threadIdx.x, ln = t & 63, wv = t >> 6;
  int wr = wv >> 2, wc = wv & 3;      // row-half, code-quarter
  int n0 = blockIdx.x * 256;
  int jb0 = blockIdx.y * 256;
  int lc = ln & 15, lq = ln >> 4;

  // --- staging descriptors (per-lane global src, wave-uniform LDS dst) ---
  const short* gA[2]; const short* gB[2]; int ldst[2];
#pragma unroll
  for (int i = 0; i < 2; i++) {
    int C = i * 512 + wv * 64 + ln;      // linear 16B chunk 0..1023
    int L = C >> 3, c5s = C & 7;
    int c5g = c5s ^ (L & 7);             // inverse swizzle on the source
    int rowg = (L << 1) | (c5g >> 2), ccg = c5g & 3;
    gA[i] = A2 + (size_t)(n0 + rowg) * 768 + ccg * 8;
    gB[i] = B2 + (size_t)(jb0 + rowg) * 768 + ccg * 8;
    ldst[i] = (i * 512 + wv * 64) * 8;   // shorts, wave-uniform
  }
  // --- LDS read offsets (shorts; constant per thread) ---
  int offA[2][4], offB[4];
#pragma unroll
  for (int rt = 0; rt < 4; rt++) {
#pragma unroll
    for (int h = 0; h < 2; h++) {
      int row = wr * 128 + h * 64 + rt * 16 + lc;
      int L = row >> 1;
      int swc = (((row & 1) << 2) + lq) ^ (L & 7);
      offA[h][rt] = L * 64 + swc * 8;
    }
    int rowb = wc * 64 + rt * 16 + lc;
    int Lb = rowb >> 1;
    int swb = (((rowb & 1) << 2) + lq) ^ (Lb & 7);
    offB[rt] = Lb * 64 + swb * 8;
  }

  f32x4 acc[8][4];
#pragma unroll
  for (int at = 0; at < 8; at++)
#pragma unroll
    for (int ac = 0; ac < 4; ac++) acc[at][ac] = (f32x4)(0.0f);

#define DSTAGE_A(tile_, bsel_)                                        \
  {                                                                   \
    _Pragma("unroll")                                                 \
    for (int i = 0; i < 2; i++)                                       \
      GLOAD_LDS(gA[i] + (tile_) * 32, &As[(bsel_)][ldst[i]]);         \
  }
#define DSTAGE_B(tile_, bsel_)                                        \
  {                                                                   \
    _Pragma("unroll")                                                 \
    for (int i = 0; i < 2; i++)                                       \
      GLOAD_LDS(gB[i] + (tile_) * 32, &Bs[(bsel_)][ldst[i]]);         \
  }

  // prologue: stage tiles 0,1,2 (12 loads/wave); vmcnt(8) -> tile0 landed
  DSTAGE_A(0, 0); DSTAGE_B(0, 0);
  DSTAGE_A(1, 1); DSTAGE_B(1, 1);
  DSTAGE_A(2, 2); DSTAGE_B(2, 2);
  asm volatile("s_waitcnt vmcnt(8)" ::: "memory");
  __builtin_amdgcn_s_barrier();

#pragma unroll
  for (int kt = 0; kt < 24; kt++) {
    const int bsel = kt & 3;
    const short* aBase = &As[bsel][0];
    const short* bBase = &Bs[bsel][0];
    // ---- P0: stage A(kt+3); read fa-half0 + all fb ----
    if (kt < 21) DSTAGE_A(kt + 3, (kt + 3) & 3);
    bf16x8 fa0[4], fb[4];
#pragma unroll
    for (int rt = 0; rt < 4; rt++)
      fa0[rt] = *(const bf16x8*)(aBase + offA[0][rt]);
#pragma unroll
    for (int ct = 0; ct < 4; ct++)
      fb[ct] = *(const bf16x8*)(bBase + offB[ct]);
    __builtin_amdgcn_s_barrier();
    asm volatile("s_waitcnt lgkmcnt(0)" ::: "memory");  // all frags resident
    __builtin_amdgcn_s_setprio(1);
#pragma unroll
    for (int rt = 0; rt < 4; rt++)
#pragma unroll
      for (int ct = 0; ct < 4; ct++)
        acc[rt][ct] = __builtin_amdgcn_mfma_f32_16x16x32_bf16(
            fa0[rt], fb[ct], acc[rt][ct], 0, 0, 0);
    __builtin_amdgcn_s_setprio(0);
    __builtin_amdgcn_s_barrier();
    // ---- P1: stage B(kt+3); read fa-half1; fb reused ----
    if (kt < 21) DSTAGE_B(kt + 3, (kt + 3) & 3);
    bf16x8 fa1[4];
#pragma unroll
    for (int rt = 0; rt < 4; rt++)
      fa1[rt] = *(const bf16x8*)(aBase + offA[1][rt]);
    __builtin_amdgcn_s_barrier();
    asm volatile("s_waitcnt lgkmcnt(0)" ::: "memory");
    __builtin_amdgcn_s_setprio(1);
#pragma unroll
    for (int rt = 0; rt < 4; rt++)
#pragma unroll
      for (int ct = 0; ct < 4; ct++)
        acc[4 + rt][ct] = __builtin_amdgcn_mfma_f32_16x16x32_bf16(
            fa1[rt], fb[ct], acc[4 + rt][ct], 0, 0, 0);
    __builtin_amdgcn_s_setprio(0);
    // ---- end of K-tile: counted wait (never 0 until the tail) ----
    if (kt < 23) {
      if (kt < 21)       { asm volatile("s_waitcnt vmcnt(8)" ::: "memory"); }
      else if (kt == 21) { asm volatile("s_waitcnt vmcnt(4)" ::: "memory"); }
      else               { asm volatile("s_waitcnt vmcnt(0)" ::: "memory"); }
      __builtin_amdgcn_s_barrier();
    }
  }
#undef DSTAGE_A
#undef DSTAGE_B

  // epilogue: dist = esq[j] - 2*dot; per-row argmin. Reuse As[0] as the
  // cross-wave reduce scratch (sbd: 4KB floats, sbi: 4KB ints) — disjoint
  // from As[3]/Bs[3] still being read by trailing waves in kt=23.
  float* sbd = (float*)(&As[0][0]);
  int*   sbi = (int*)((char*)(&As[0][0]) + 4096);

#pragma unroll
  for (int at = 0; at < 8; at++) {
    float bst[4]; int bix[4];
#pragma unroll
    for (int r = 0; r < 4; r++) { bst[r] = 3.4e38f; bix[r] = 0; }
#pragma unroll
    for (int ac = 0; ac < 4; ac++) {
      int j = jb0 + wc * 64 + ac * 16 + lc;
      float es = esq[j];
#pragma unroll
      for (int r = 0; r < 4; r++) {
        float d = es - 2.0f * acc[at][ac][r];
        if (d < bst[r]) { bst[r] = d; bix[r] = j; }  // ac asc => j asc, '<' keeps low j
      }
    }
#pragma unroll
    for (int r = 0; r < 4; r++) {
      float bd = bst[r]; int bi = bix[r];
#pragma unroll
      for (int off = 1; off < 16; off <<= 1) {
        float od = __shfl_xor(bd, off, 64);
        int   oi = __shfl_xor(bi, off, 64);
        if (od < bd || (od == bd && oi < bi)) { bd = od; bi = oi; }
      }
      if (lc == 0) {
        int rl = wr * 128 + at * 16 + lq * 4 + r;
        sbd[wc * 256 + rl] = bd;
        sbi[wc * 256 + rl] = bi;
      }
    }
  }
  __syncthreads();
  // combine the 4 code-quarters (wc ascending = ascending j; explicit tiebreak)
  if (t < 256) {
    float b0 = sbd[t]; int i0 = sbi[t];
#pragma unroll
    for (int w = 1; w < 4; w++) {
      float b1 = sbd[w * 256 + t]; int i1 = sbi[w * 256 + t];
      if (b1 < b0 || (b1 == b0 && i1 < i0)) { b0 = b1; i0 = i1; }
    }
    int n = n0 + t;
    if (n < N) {
      pd[(size_t)n * 32 + blockIdx.y] = b0;
      pi[(size_t)n * 32 + blockIdx.y] = i0;
    }
  }
}

// reduce per-row partials over 32 code tiles -> idx, counts
__global__ void k_red(const float* __restrict__ pd, const int* __restrict__ pi,
                      int* __restrict__ idxb, float* __restrict__ counts, int N, int nct) {
  int n = blockIdx.x * 256 + threadIdx.x;
  if (n >= N) return;
  float bd = pd[(size_t)n * nct]; int bi = pi[(size_t)n * nct];
  for (int jt = 1; jt < nct; jt++) {
    float d = pd[(size_t)n * nct + jt]; int ii = pi[(size_t)n * nct + jt];
    if (d < bd || (d == bd && ii < bi)) { bd = d; bi = ii; }
  }
  idxb[n] = bi;
  atomicAdd(counts + bi, 1.0f);
}

// gather + bicubic upsample -> zu fp32 NHWC and zu2 compensated [hi,lo,hi]
__global__ void k_up(const float* __restrict__ emb, const int* __restrict__ idxb,
                     float* __restrict__ zu, short* __restrict__ zu2, int pn, int last) {
  int n = blockIdx.x, c = threadIdx.x;
  float acc;
  if (last) {
    acc = emb[(size_t)idxb[n] * 256 + c];
  } else {
    int b = n >> 8, hw = n & 255, h = hw >> 4, w = hw & 15;
    float scale = pn / 16.0f;
    float xh = (h + 0.5f) * scale - 0.5f; int fh = (int)floorf(xh);
    float xw = (w + 0.5f) * scale - 0.5f; int fw = (int)floorf(xw);
    int ph[4], pw[4]; float wh[4], wwt[4];
#pragma unroll
    for (int k = 0; k < 4; k++) {
      wh[k] = cubicw(xh - (float)(fh + k - 1));
      int pp = fh + k - 1; ph[k] = min(max(pp, 0), pn - 1);
      wwt[k] = cubicw(xw - (float)(fw + k - 1));
      pp = fw + k - 1; pw[k] = min(max(pp, 0), pn - 1);
    }
    acc = 0.0f;
#pragma unroll
    for (int kh = 0; kh < 4; kh++)
#pragma unroll
      for (int kw = 0; kw < 4; kw++) {
        int row = idxb[(n >> 8) * pn * pn + ph[kh] * pn + pw[kw]];
        acc += wh[kh] * wwt[kw] * emb[(size_t)row * 256 + c];
      }
  }
  zu[(size_t)n * 256 + c] = acc;
  short hi = f2bf(acc);
  short lo = f2bf(acc - bf2f(hi));
  zu2[(size_t)n * 768 + c]       = hi;
  zu2[(size_t)n * 768 + 256 + c] = lo;
  zu2[(size_t)n * 768 + 512 + c] = hi;
}

// 3x3 SAME conv as compensated-bf16 MFMA GEMM — R19: R16 structure with
// DEEP B prefetch. Diagnosis: R16's ring-3 staged s+2 and waited vmcnt(4)
// forcing the s+1 panel issued only ONE step (~600cy) earlier — a per-step
// load-latency stall x108 steps (conv ~17% peak vs dist 29%). Fix mirrors
// dist's proven depth-3: B ring-4 (stage s+3), steady-state vmcnt(8)
// (robust: forces the needed panel even with 4 halo loads in the window,
// over-forcing at worst a 1-step-old panel). LDS funding: halo single-
// buffered (+1 post-MFMA barrier at tap8 before rewrite — by construction
// all waves' halo reads are complete there), epilogue red[] reuses Ah.
// LDS = 13.5K halo + 64K B = 77.5KB -> 2 blocks/CU kept. Math identical.
__global__ __launch_bounds__(256, 2) void k_conv_mfma(
    const short* __restrict__ zu2, const short* __restrict__ wB2,
    const float* __restrict__ cb, const float* __restrict__ zu,
    float* __restrict__ zrest, float* __restrict__ out_loss, int si) {
  __shared__ short Ah[108 * 64];      // 13.5 KB (6*18 halo rows x 64 sh)
  __shared__ short Bs[4][128 * 64];   // 64 KB ring-4
  int t = threadIdx.x, ln = t & 63, wv = t >> 6;
  int pxh = wv >> 1, oq = wv & 1;
  int lc = ln & 15, lq = ln >> 4;
  int b = blockIdx.x >> 2, h0 = (blockIdx.x & 3) * 4;
  int o0 = blockIdx.y * 128;

  // per-thread A-halo staging descriptors (4 chunks of 16B; kc-invariant)
  bool awr[4], aval[4]; const short* asrc[4]; int adst[4];
#pragma unroll
  for (int i = 0; i < 4; i++) {
    int c = i * 256 + t;               // 0..1023; halo has 864 chunks
    int rh = c >> 3, cc = c & 7;
    int hh = rh / 18, wx = rh - hh * 18;
    int h = h0 + hh - 1, w = wx - 1;
    awr[i]  = (c < 864);
    aval[i] = awr[i] && (h >= 0) && (h < 16) && (w >= 0) && (w < 16);
    int n = aval[i] ? (b * 256 + h * 16 + w) : 0;
    asrc[i] = zu2 + (size_t)n * 768 + cc * 8;
    adst[i] = rh * 64 + (cc ^ (rh & 7)) * 8;
  }

// stage B panel (tap nt_, k-chunk nk_) into ring slot bsel_ (4 calls/thread)
#define CSTAGE(nt_, nk_, bsel_)                                             \
  {                                                                         \
    const short* bbase =                                                    \
        wB2 + (((size_t)si * 9 + (nt_)) * 256 + o0) * 768 + (nk_) * 64;     \
    _Pragma("unroll")                                                       \
    for (int i = 0; i < 4; i++) {                                           \
      int Lb = i * 256 + wv * 64;                                           \
      int L = Lb + ln;                                                      \
      int row = L >> 3, cc = L & 7;                                         \
      int gc = cc ^ (row & 7);                                              \
      GLOAD_LDS(bbase + (size_t)row * 768 + gc * 8, &Bs[(bsel_)][Lb * 8]);  \
    }                                                                       \
  }

  f32x4 acc[2][4];
#pragma unroll
  for (int pf = 0; pf < 2; pf++)
#pragma unroll
    for (int ct = 0; ct < 4; ct++) acc[pf][ct] = (f32x4)(0.0f);

  // ---- prologue: halo kc0 (reg loads) + panels 0,1,2 staged ----
  {
    uint4 a[4];
#pragma unroll
    for (int i = 0; i < 4; i++) {
      a[i] = make_uint4(0u, 0u, 0u, 0u);
      if (aval[i]) a[i] = *(const uint4*)(asrc[i]);
    }
    CSTAGE(0, 0, 0);
    CSTAGE(1, 0, 1);
    CSTAGE(2, 0, 2);
    asm volatile("s_waitcnt vmcnt(12)" ::: "memory");  // forces 4 halo loads
#pragma unroll
    for (int i = 0; i < 4; i++)
      if (awr[i]) *(uint4*)(&Ah[adst[i]]) = a[i];
    asm volatile("s_waitcnt vmcnt(8) lgkmcnt(0)" ::: "memory");  // panel0+halo
  }
  __builtin_amdgcn_s_barrier();

  for (int kc = 0; kc < 12; kc++) {
    uint4 na[4];
#pragma unroll
    for (int i = 0; i < 4; i++) na[i] = make_uint4(0u, 0u, 0u, 0u);
#pragma unroll
    for (int tap = 0; tap < 9; tap++) {
      const int s = kc * 9 + tap;      // step index 0..107
      const int rb4 = s & 3;           // read ring slot
      const int sb4 = (s + 3) & 3;     // stage ring slot
      int dh = tap / 3 - 1, dw = tap % 3 - 1;
      // --- fragment reads for this step ---
      bf16x8 fa[2][2], fb[2][4];
#pragma unroll
      for (int ks = 0; ks < 2; ks++) {
#pragma unroll
        for (int pf = 0; pf < 2; pf++) {
          int rh = (pxh * 2 + pf + dh + 1) * 18 + lc + dw + 1;
          int cc = (ks * 4 + lq) ^ (rh & 7);
          fa[ks][pf] = *(const bf16x8*)(&Ah[rh * 64 + cc * 8]);
        }
#pragma unroll
        for (int ct = 0; ct < 4; ct++) {
          int row = oq * 64 + ct * 16 + lc;
          int cc = (ks * 4 + lq) ^ (lc & 7);
          fb[ks][ct] = *(const bf16x8*)(&Bs[rb4][row * 64 + cc * 8]);
        }
      }
      // --- stage B panel for step s+3 (s+3 <= 107) ---
      if (s <= 104) {
        int nt = (tap <= 5) ? tap + 3 : tap - 6;
        int nk = (tap <= 5) ? kc : kc + 1;
        CSTAGE(nt, nk, sb4);
      }
      // --- halo pipeline: issue next-kc loads at tap 0 ---
      if (tap == 0 && kc < 11) {
        int koff = (kc + 1) * 64;
#pragma unroll
        for (int i = 0; i < 4; i++)
          if (aval[i]) na[i] = *(const uint4*)(asrc[i] + koff);
      }
      __builtin_amdgcn_s_barrier();
      asm volatile("s_waitcnt lgkmcnt(0)" ::: "memory");  // frags resident
      __builtin_amdgcn_s_setprio(1);
#pragma unroll
      for (int ks = 0; ks < 2; ks++)
#pragma unroll
        for (int pf = 0; pf < 2; pf++)
#pragma unroll
          for (int ct = 0; ct < 4; ct++)
            acc[pf][ct] = __builtin_amdgcn_mfma_f32_16x16x32_bf16(
                fa[ks][pf], fb[ks][ct], acc[pf][ct], 0, 0, 0);
      __builtin_amdgcn_s_setprio(0);
      // --- tap8: single-buffer halo rewrite (all waves past lgkm(0) =>
      //     all halo reads complete; barrier makes that global) ---
      if (tap == 8 && kc < 11) {
        __builtin_amdgcn_s_barrier();
#pragma unroll
        for (int i = 0; i < 4; i++)
          if (awr[i]) *(uint4*)(&Ah[adst[i]]) = na[i];
      }
      // --- end of step: counted wait; lgkm drain at tap8 (halo writes) ---
      if (s < 107) {
        if (s <= 104) {
          if (tap == 8) { asm volatile("s_waitcnt vmcnt(8) lgkmcnt(0)" ::: "memory"); }
          else          { asm volatile("s_waitcnt vmcnt(8)" ::: "memory"); }
        } else if (s == 105) {
          asm volatile("s_waitcnt vmcnt(4)" ::: "memory");
        } else {  // s == 106
          asm volatile("s_waitcnt vmcnt(0)" ::: "memory");
        }
        __builtin_amdgcn_s_barrier();
      }
    }
  }
#undef CSTAGE
  __syncthreads();

  // --- epilogue: bias + residual update + loss (red reuses Ah) ---
  float* red = (float*)Ah;
  float lsum = 0.0f;
#pragma unroll
  for (int ct = 0; ct < 4; ct++) {
    int o = o0 + oq * 64 + ct * 16 + lc;
    float bias = cb[si * 256 + o];
#pragma unroll
    for (int pf = 0; pf < 2; pf++) {
      int n = b * 256 + (h0 + pxh * 2 + pf) * 16;
#pragma unroll
      for (int r = 0; r < 4; r++) {
        size_t m = (size_t)(n + lq * 4 + r) * 256 + o;
        float y = acc[pf][ct][r] + bias;
        float res = 0.5f * (zu[m] + y);
        float nv = zrest[m] - res;
        zrest[m] = nv;
        lsum += nv * nv;
      }
    }
  }
  red[t] = lsum;
  __syncthreads();
  for (int s = 128; s > 0; s >>= 1) { if (t < s) red[t] += red[t + s]; __syncthreads(); }
  if (t == 0) atomicAdd(out_loss, red[0] * (0.25f / (8.0f * 4194304.0f)));
}

// out NCHW = z - z_rest (z_hat_cum)
__global__ void k_out(const float* __restrict__ z, const float* __restrict__ zrest,
                      float* __restrict__ out) {
  int n = blockIdx.x, c = threadIdx.x;
  int b = n >> 8, hw = n & 255;
  size_t m = ((size_t)(b * 256 + c)) * 256 + hw;
  out[m] = z[m] - zrest[(size_t)n * 256 + c];
}

// ---------------- launch ----------------
extern "C" void kernel_launch(void* const* d_in, const int* in_sizes, int n_in,
                              void* d_out, int out_size, void* d_ws, size_t ws_size,
                              hipStream_t stream) {
  const float* z   = (const float*)d_in[0];
  const float* emb = (const float*)d_in[1];
  const float* cw  = (const float*)d_in[2];
  const float* cb  = (const float*)d_in[3];
  float* out = (float*)d_out;
  float* ws  = (float*)d_ws;

  // layout: 25,976,832 floats = 103.9 MB (proven-safe envelope: R1 used 112 MB)
  float* z_rest = ws;                        // 4,194,304
  float* zu     = ws + 4194304;              // 4,194,304
  float* esq    = ws + 8388608;              // 8,192
  short* A2     = (short*)(ws + 8396800);    // 16384*768 shorts = 6,291,456 floats
  short* zu2    = A2;                        // reuses A2 (free after dist)
  short* B2     = (short*)(ws + 14688256);   // 8192*768 shorts  = 3,145,728 floats
  short* wB2    = (short*)(ws + 17833984);   // 8*9*256*768 shorts = 7,077,888 floats
  float* pd     = ws + 24911872;             // 16384*32 = 524,288
  int*   pi     = (int*)(ws + 25436160);     // 524,288
  int*   idxb   = (int*)(ws + 25960448);     // 16,384

  const int pns[8] = {1, 2, 3, 4, 6, 8, 12, 16};

  k_zero<<<33, 256, 0, stream>>>(out + LOSS_OFF, 1 + NE);
  k_tr_in<<<16384, 256, 0, stream>>>(z, z_rest);
  k_prep_emb2<<<8192, 256, 0, stream>>>(emb, B2, esq);
  k_prep_wb<<<18432, 256, 0, stream>>>(cw, wB2);

  for (int si = 0; si < 8; si++) {
    int pn = pns[si];
    int N = 64 * pn * pn;
    if (si < 7)
      k_down_a2<<<dim3(pn * pn, 64), 256, 0, stream>>>(z_rest, A2, pn);
    else
      k_split_a2<<<16384, 256, 0, stream>>>(z_rest, A2);
    int rb = (N + 255) / 256;
    k_dist_mfma<<<dim3(rb, 32), 512, 0, stream>>>(A2, B2, esq, pd, pi, N);
    k_red<<<(N + 255) / 256, 256, 0, stream>>>(pd, pi, idxb, out + CNT_OFF, N, 32);
    k_up<<<16384, 256, 0, stream>>>(emb, idxb, zu, zu2, pn, si == 7 ? 1 : 0);
    k_conv_mfma<<<dim3(256, 2), 256, 0, stream>>>(zu2, wB2, cb, zu, z_rest,
                                                  out + LOSS_OFF, si);
  }
  k_out<<<16384, 256, 0, stream>>>(z, z_rest, out);
}